// Round 1
// baseline (9177.779 us; speedup 1.0000x reference)
//
#include <hip/hip_runtime.h>
#include <hip/hip_bf16.h>
#include <math.h>

#define NI 64
#define NC 64
#define NTOK 197
#define TT 196
#define CL 32
#define DD 1024
#define SS 256
#define NN 33
#define EPSN 1e-12f
#define SMOOTHF 9.0f
#define SMEM_BYTES 76048

__device__ __forceinline__ float warp_reduce_sum64(float v) {
#pragma unroll
  for (int m = 32; m > 0; m >>= 1) v += __shfl_xor(v, m, 64);
  return v;
}

// ---------------------------------------------------------------- K1: means
__global__ void k_avg(const float* __restrict__ img, const float* __restrict__ cap,
                      float* __restrict__ img_avg, float* __restrict__ cap_avg) {
  int bid = blockIdx.x;
  int tid = threadIdx.x;
  if (bid < NI) {
    int b = bid;
    for (int d = tid; d < DD; d += 256) {
      float acc = 0.f;
      const float* p = img + ((size_t)b * NTOK + 1) * DD + d;
      for (int t = 0; t < TT; ++t) acc += p[(size_t)t * DD];
      img_avg[b * DD + d] = acc * (1.0f / TT);
    }
  } else {
    int c = bid - NI;
    for (int d = tid; d < DD; d += 256) {
      float acc = 0.f;
      const float* p = cap + (size_t)c * CL * DD + d;
      for (int t = 0; t < CL; ++t) acc += p[(size_t)t * DD];
      cap_avg[c * DD + d] = acc * (1.0f / CL);
    }
  }
}

// ------------------------------------------------- K2: h = tanh(avg@Wg+bg)*Wc
__global__ void k_hvec(const float* __restrict__ avg, const float* __restrict__ Wg,
                       const float* __restrict__ bg, const float* __restrict__ Wc,
                       float* __restrict__ h) {
  __shared__ float av[DD];
  int b = blockIdx.x >> 2;
  int dc = blockIdx.x & 3;
  int tid = threadIdx.x;
  for (int i = tid; i < DD; i += 256) av[i] = avg[b * DD + i];
  __syncthreads();
  int d = dc * 256 + tid;
  float acc = 0.f;
  for (int k = 0; k < DD; k += 4) {
    float4 a4 = *(const float4*)&av[k];
    acc += a4.x * Wg[(size_t)(k + 0) * DD + d];
    acc += a4.y * Wg[(size_t)(k + 1) * DD + d];
    acc += a4.z * Wg[(size_t)(k + 2) * DD + d];
    acc += a4.w * Wg[(size_t)(k + 3) * DD + d];
  }
  h[b * DD + d] = tanhf(acc + bg[d]) * Wc[d];
}

// ---------------- K3: partial[row,ct] = sum_{d in col-tile} tanh((A@Wl)[row,d]+bl)*h[b,d]
__global__ void k_logits_partial(const float* __restrict__ Abase, long batchStride, int rowsPerBatch,
                                 const float* __restrict__ Wl, const float* __restrict__ bl,
                                 const float* __restrict__ h, float* __restrict__ partial) {
  __shared__ float a_lds[32][68];
  __shared__ float b_lds[32][68];
  int tid = threadIdx.x;
  int rb = blockIdx.x * 64;
  int c0 = blockIdx.y * 64;
  int ty = tid >> 4, tx = tid & 15;
  int s_rr = tid >> 2, s_kq = tid & 3;
  int rA = rb + s_rr;
  const float* aRow = Abase + (size_t)(rA / rowsPerBatch) * batchStride + (size_t)(rA % rowsPerBatch) * DD;
  int s_kk = tid >> 3, s_cq = tid & 7;
  float acc[4][4] = {};
  for (int k0 = 0; k0 < DD; k0 += 32) {
    float4 v0 = *(const float4*)&aRow[k0 + s_kq * 8];
    float4 v1 = *(const float4*)&aRow[k0 + s_kq * 8 + 4];
    float4 w0 = *(const float4*)&Wl[(size_t)(k0 + s_kk) * DD + c0 + s_cq * 8];
    float4 w1 = *(const float4*)&Wl[(size_t)(k0 + s_kk) * DD + c0 + s_cq * 8 + 4];
    __syncthreads();
    float va[8] = {v0.x, v0.y, v0.z, v0.w, v1.x, v1.y, v1.z, v1.w};
#pragma unroll
    for (int u = 0; u < 8; ++u) a_lds[s_kq * 8 + u][s_rr] = va[u];
    *(float4*)&b_lds[s_kk][s_cq * 8] = w0;
    *(float4*)&b_lds[s_kk][s_cq * 8 + 4] = w1;
    __syncthreads();
#pragma unroll
    for (int kk = 0; kk < 32; ++kk) {
      float4 a4 = *(const float4*)&a_lds[kk][ty * 4];
      float4 b4 = *(const float4*)&b_lds[kk][tx * 4];
      float av[4] = {a4.x, a4.y, a4.z, a4.w};
      float bv[4] = {b4.x, b4.y, b4.z, b4.w};
#pragma unroll
      for (int i = 0; i < 4; ++i)
#pragma unroll
        for (int j = 0; j < 4; ++j) acc[i][j] += av[i] * bv[j];
    }
  }
#pragma unroll
  for (int i = 0; i < 4; ++i) {
    int r = rb + ty * 4 + i;
    int bb = r / rowsPerBatch;
    float s = 0.f;
#pragma unroll
    for (int j = 0; j < 4; ++j) {
      int cc = c0 + tx * 4 + j;
      s += tanhf(acc[i][j] + bl[cc]) * h[bb * DD + cc];
    }
    s += __shfl_xor(s, 1, 64);
    s += __shfl_xor(s, 2, 64);
    s += __shfl_xor(s, 4, 64);
    s += __shfl_xor(s, 8, 64);
    if (tx == 0) partial[(size_t)r * 16 + blockIdx.y] = s;
  }
}

// -------- K4: logits -> softmax weights -> weighted sum of tokens -> l2norm
__global__ void k_finish_global(const float* __restrict__ partial, const float* __restrict__ bc,
                                const float* __restrict__ Xbase, long batchStride, int R,
                                float* __restrict__ outG) {
  __shared__ float w[200];
  __shared__ float red[8];
  int b = blockIdx.x, tid = threadIdx.x;
  for (int t = tid; t < R; t += 256) {
    const float* pp = &partial[((size_t)b * R + t) * 16];
    float s = bc[0];
#pragma unroll
    for (int u = 0; u < 16; ++u) s += pp[u];
    w[t] = s;
  }
  __syncthreads();
  float m = -1e30f;
  for (int t = tid; t < R; t += 256) m = fmaxf(m, w[t]);
#pragma unroll
  for (int mm = 32; mm; mm >>= 1) m = fmaxf(m, __shfl_xor(m, mm, 64));
  if ((tid & 63) == 0) red[tid >> 6] = m;
  __syncthreads();
  m = fmaxf(fmaxf(red[0], red[1]), fmaxf(red[2], red[3]));
  __syncthreads();
  for (int t = tid; t < R; t += 256) w[t] = expf(w[t] - m);
  __syncthreads();
  const float* xb = Xbase + (size_t)b * batchStride;
  float acc[4];
  float ss = 0.f;
#pragma unroll
  for (int c4 = 0; c4 < 4; ++c4) {
    int d = tid + c4 * 256;
    float a = 0.f;
    for (int t = 0; t < R; ++t) a += w[t] * xb[(size_t)t * DD + d];
    acc[c4] = a;
    ss += a * a;
  }
  ss = warp_reduce_sum64(ss);
  if ((tid & 63) == 0) red[tid >> 6] = ss;
  __syncthreads();
  ss = red[0] + red[1] + red[2] + red[3];
  float rn = 1.0f / fmaxf(sqrtf(ss), EPSN);
#pragma unroll
  for (int c4 = 0; c4 < 4; ++c4) outG[(size_t)b * DD + tid + c4 * 256] = acc[c4] * rn;
}

// -------- K5: sim_glo[p] = l2norm((img_g[b]-cap_g[c])^2 @ W_glo + b_glo), p=b*64+c
__global__ void k_simglo(const float* __restrict__ ig, const float* __restrict__ cg,
                         const float* __restrict__ W, const float* __restrict__ bgl,
                         float* __restrict__ simglo) {
  __shared__ float a_lds[32][20];
  __shared__ float b_lds[32][260];
  int tid = threadIdx.x;
  int p0 = blockIdx.x * 16;
  int ty = tid >> 6, tx = tid & 63;
  int s_rr = tid >> 3, s_kq = tid & 7;
  float acc[4][4] = {};
  for (int k0 = 0; k0 < DD; k0 += 32) {
    float d2[4] = {};
    if (tid < 128) {
      int p = p0 + s_rr;
      int b = p >> 6, c = p & 63;
      float4 giv = *(const float4*)&ig[b * DD + k0 + s_kq * 4];
      float4 cgv = *(const float4*)&cg[c * DD + k0 + s_kq * 4];
      float dx = giv.x - cgv.x, dy = giv.y - cgv.y, dz = giv.z - cgv.z, dw = giv.w - cgv.w;
      d2[0] = dx * dx; d2[1] = dy * dy; d2[2] = dz * dz; d2[3] = dw * dw;
    }
    float4 wv[8];
#pragma unroll
    for (int u = 0; u < 8; ++u)
      wv[u] = *(const float4*)&W[(size_t)(k0 + s_rr) * SS + s_kq * 32 + u * 4];
    __syncthreads();
    if (tid < 128) {
#pragma unroll
      for (int u = 0; u < 4; ++u) a_lds[s_kq * 4 + u][s_rr] = d2[u];
    }
#pragma unroll
    for (int u = 0; u < 8; ++u)
      *(float4*)&b_lds[s_rr][s_kq * 32 + u * 4] = wv[u];
    __syncthreads();
#pragma unroll
    for (int kk = 0; kk < 32; ++kk) {
      float4 a4 = *(const float4*)&a_lds[kk][ty * 4];
      float4 b4 = *(const float4*)&b_lds[kk][tx * 4];
      float av[4] = {a4.x, a4.y, a4.z, a4.w};
      float bv[4] = {b4.x, b4.y, b4.z, b4.w};
#pragma unroll
      for (int i = 0; i < 4; ++i)
#pragma unroll
        for (int j = 0; j < 4; ++j) acc[i][j] += av[i] * bv[j];
    }
  }
#pragma unroll
  for (int i = 0; i < 4; ++i) {
    float v[4];
    float ssq = 0.f;
#pragma unroll
    for (int j = 0; j < 4; ++j) {
      v[j] = acc[i][j] + bgl[tx * 4 + j];
      ssq += v[j] * v[j];
    }
    ssq = warp_reduce_sum64(ssq);
    float rn = 1.0f / fmaxf(sqrtf(ssq), EPSN);
    int p = p0 + ty * 4 + i;
    *(float4*)&simglo[(size_t)p * SS + tx * 4] =
        make_float4(v[0] * rn, v[1] * rn, v[2] * rn, v[3] * rn);
  }
}

// -------- K6: M[t] = Wq_t @ Wk_t^T  (256x256)
__global__ void k_mmat(const float* __restrict__ Wq, const float* __restrict__ Wk,
                       float* __restrict__ M) {
  __shared__ float a_lds[32][68];
  __shared__ float b_lds[32][68];
  int tid = threadIdx.x;
  int t = blockIdx.x >> 4;
  int dt = (blockIdx.x >> 2) & 3, et = blockIdx.x & 3;
  int d0 = dt * 64, e0 = et * 64;
  const float* wq = Wq + (size_t)t * SS * SS;
  const float* wk = Wk + (size_t)t * SS * SS;
  int ty = tid >> 4, tx = tid & 15;
  int s_rr = tid >> 2, s_kq = tid & 3;
  float acc[4][4] = {};
  for (int j0 = 0; j0 < SS; j0 += 32) {
    float4 q0 = *(const float4*)&wq[(size_t)(d0 + s_rr) * SS + j0 + s_kq * 8];
    float4 q1 = *(const float4*)&wq[(size_t)(d0 + s_rr) * SS + j0 + s_kq * 8 + 4];
    float4 k0v = *(const float4*)&wk[(size_t)(e0 + s_rr) * SS + j0 + s_kq * 8];
    float4 k1v = *(const float4*)&wk[(size_t)(e0 + s_rr) * SS + j0 + s_kq * 8 + 4];
    __syncthreads();
    float qa[8] = {q0.x, q0.y, q0.z, q0.w, q1.x, q1.y, q1.z, q1.w};
    float ka[8] = {k0v.x, k0v.y, k0v.z, k0v.w, k1v.x, k1v.y, k1v.z, k1v.w};
#pragma unroll
    for (int u = 0; u < 8; ++u) {
      a_lds[s_kq * 8 + u][s_rr] = qa[u];
      b_lds[s_kq * 8 + u][s_rr] = ka[u];
    }
    __syncthreads();
#pragma unroll
    for (int kk = 0; kk < 32; ++kk) {
      float4 a4 = *(const float4*)&a_lds[kk][ty * 4];
      float4 b4 = *(const float4*)&b_lds[kk][tx * 4];
      float av[4] = {a4.x, a4.y, a4.z, a4.w};
      float bv[4] = {b4.x, b4.y, b4.z, b4.w};
#pragma unroll
      for (int i = 0; i < 4; ++i)
#pragma unroll
        for (int j = 0; j < 4; ++j) acc[i][j] += av[i] * bv[j];
    }
  }
#pragma unroll
  for (int i = 0; i < 4; ++i)
    *(float4*)&M[(size_t)t * SS * SS + (size_t)(d0 + ty * 4 + i) * SS + e0 + tx * 4] =
        make_float4(acc[i][0], acc[i][1], acc[i][2], acc[i][3]);
}

// -------- K6b: wkbq[t] = Wk_t @ bq_t
__global__ void k_wkbq(const float* __restrict__ Wk, const float* __restrict__ bq,
                       float* __restrict__ out) {
  __shared__ float bv[SS];
  int t = blockIdx.x, tid = threadIdx.x;
  const float* wk = Wk + (size_t)t * SS * SS;
  bv[tid] = bq[t * SS + tid];
  __syncthreads();
  float acc = 0.f;
  for (int j = 0; j < SS; j += 4) {
    float4 wv = *(const float4*)&wk[(size_t)tid * SS + j];
    float4 b4 = *(const float4*)&bv[j];
    acc += wv.x * b4.x + wv.y * b4.y + wv.z * b4.z + wv.w * b4.w;
  }
  out[t * SS + tid] = acc;
}

// -------- K7: per-(img,cap) pair mega kernel
__global__ __launch_bounds__(256) void k_pair(
    const float* __restrict__ img, const float* __restrict__ cap,
    const float* __restrict__ W_loc, const float* __restrict__ b_loc,
    const float* __restrict__ simglo, const float* __restrict__ M,
    const float* __restrict__ wkbq, const float* __restrict__ Wg3,
    const float* __restrict__ bg3, const float* __restrict__ W_eval,
    const float* __restrict__ b_eval, float* __restrict__ out) {
  extern __shared__ char smem[];
  float* attn = (float*)smem;                   // [196][33]
  float* imgA = (float*)(smem + 25872);         // [32][68] (phase A)
  float* capA = (float*)(smem + 34576);         // [32][36] (phase A)
  float* wtile = (float*)(smem + 25872);        // [32][132] (phase W)
  float* imgK = (float*)(smem + 42768);         // [32][132] (phase W)
  float* wloc = (float*)(smem + 42768);         // [32][260] (phase W, time-shared)
  float* seA = (float*)smem;                    // [33][260] (SGR)
  float* seB = (float*)(smem + 34320);          // [33][260] (SGR)
  float* Emat = (float*)(smem + 68640);         // [33][36]
  float* vbuf = (float*)(smem + 73392);         // [33]
  float* wkbqs = (float*)(smem + 73536);        // [256]

  int tid = threadIdx.x;
  int p = blockIdx.x;
  int b = p >> 6, c = p & 63;
  const float* imgB = img + ((size_t)b * NTOK + 1) * DD;
  const float* capC = cap + (size_t)c * CL * DD;

  // ---------------- Phase A: attn[t][q] = img_tok[t] . cap[q], leaky relu
  {
    int tg = tid & 15, qg = tid >> 4;
    int s_rr = tid >> 2, s_kq = tid & 3;
    int s_q = tid >> 2, s_kq2 = tid & 3;  // cap staging (tid<128)
    for (int T0 = 0; T0 < TT; T0 += 64) {
      float acc[4][2] = {};
      for (int k0 = 0; k0 < DD; k0 += 32) {
        int trow = T0 + s_rr;
        float4 v0 = {}, v1 = {};
        if (trow < TT) {
          v0 = *(const float4*)&imgB[(size_t)trow * DD + k0 + s_kq * 8];
          v1 = *(const float4*)&imgB[(size_t)trow * DD + k0 + s_kq * 8 + 4];
        }
        float4 c0v = {}, c1v = {};
        if (tid < 128) {
          c0v = *(const float4*)&capC[(size_t)s_q * DD + k0 + s_kq2 * 8];
          c1v = *(const float4*)&capC[(size_t)s_q * DD + k0 + s_kq2 * 8 + 4];
        }
        __syncthreads();
        {
          float va[8] = {v0.x, v0.y, v0.z, v0.w, v1.x, v1.y, v1.z, v1.w};
#pragma unroll
          for (int u = 0; u < 8; ++u) imgA[(s_kq * 8 + u) * 68 + s_rr] = va[u];
          if (tid < 128) {
            float ca[8] = {c0v.x, c0v.y, c0v.z, c0v.w, c1v.x, c1v.y, c1v.z, c1v.w};
#pragma unroll
            for (int u = 0; u < 8; ++u) capA[(s_kq2 * 8 + u) * 36 + s_q] = ca[u];
          }
        }
        __syncthreads();
#pragma unroll
        for (int kk = 0; kk < 32; ++kk) {
          float4 a4 = *(const float4*)&imgA[kk * 68 + tg * 4];
          float2 c2 = *(const float2*)&capA[kk * 36 + qg * 2];
          float av[4] = {a4.x, a4.y, a4.z, a4.w};
          float cv[2] = {c2.x, c2.y};
#pragma unroll
          for (int i = 0; i < 4; ++i)
#pragma unroll
            for (int j = 0; j < 2; ++j) acc[i][j] += av[i] * cv[j];
        }
      }
#pragma unroll
      for (int i = 0; i < 4; ++i) {
        int t = T0 + tg * 4 + i;
        if (t < TT) {
#pragma unroll
          for (int j = 0; j < 2; ++j) {
            float v = acc[i][j];
            v = v < 0.f ? 0.1f * v : v;
            attn[t * 33 + qg * 2 + j] = v;
          }
        }
      }
      __syncthreads();
    }
  }

  // ---------------- Phase A2: l2norm over q per token row t
  if (tid < TT) {
    float ss = 0.f;
#pragma unroll
    for (int q = 0; q < 32; ++q) {
      float v = attn[tid * 33 + q];
      ss += v * v;
    }
    float rn = 1.0f / fmaxf(sqrtf(ss), EPSN);
#pragma unroll
    for (int q = 0; q < 32; ++q) attn[tid * 33 + q] *= rn;
  }
  __syncthreads();

  // ---------------- Phase A3: softmax (x9) over t per q (denominator dropped)
  {
    int q = tid >> 3, sub = tid & 7;
    float m = -1e30f;
    for (int t = sub; t < TT; t += 8) m = fmaxf(m, attn[t * 33 + q]);
    m = fmaxf(m, __shfl_xor(m, 1, 64));
    m = fmaxf(m, __shfl_xor(m, 2, 64));
    m = fmaxf(m, __shfl_xor(m, 4, 64));
    for (int t = sub; t < TT; t += 8)
      attn[t * 33 + q] = expf(SMOOTHF * (attn[t * 33 + q] - m));
  }
  __syncthreads();

  // ---------------- Phase W: weighted ctx, diff^2, sim_loc = diff2 @ W_loc
  float sl[4][8] = {};
  {
    int qg = tid & 7, dg = tid >> 3;
    int s_tt = tid >> 3, s_dq = tid & 7;
    int sq = tid >> 5, sg = tid & 31;
    int l_dd = tid >> 3, l_cq = tid & 7;
    for (int d0 = 0; d0 < DD; d0 += 128) {
      float wa[4][4] = {};
      for (int t0 = 0; t0 < TT; t0 += 32) {
        int kn = TT - t0;
        kn = kn > 32 ? 32 : kn;
        int trow = t0 + s_tt;
        float4 iv[4] = {};
        if (trow < TT) {
#pragma unroll
          for (int u = 0; u < 4; ++u)
            iv[u] = *(const float4*)&imgB[(size_t)trow * DD + d0 + s_dq * 16 + u * 4];
        }
        __syncthreads();
#pragma unroll
        for (int u = 0; u < 4; ++u)
          *(float4*)&imgK[s_tt * 132 + s_dq * 16 + u * 4] = iv[u];
        __syncthreads();
        for (int kk = 0; kk < kn; ++kk) {
          float a0 = attn[(t0 + kk) * 33 + qg * 4 + 0];
          float a1 = attn[(t0 + kk) * 33 + qg * 4 + 1];
          float a2 = attn[(t0 + kk) * 33 + qg * 4 + 2];
          float a3 = attn[(t0 + kk) * 33 + qg * 4 + 3];
          float4 i4 = *(const float4*)&imgK[kk * 132 + dg * 4];
          float av[4] = {a0, a1, a2, a3};
          float ivv[4] = {i4.x, i4.y, i4.z, i4.w};
#pragma unroll
          for (int i = 0; i < 4; ++i)
#pragma unroll
            for (int j = 0; j < 4; ++j) wa[i][j] += av[i] * ivv[j];
        }
        __syncthreads();
      }
#pragma unroll
      for (int i = 0; i < 4; ++i)
        *(float4*)&wtile[(qg * 4 + i) * 132 + dg * 4] =
            make_float4(wa[i][0], wa[i][1], wa[i][2], wa[i][3]);
      __syncthreads();
      for (int idx = tid; idx < 32 * 128; idx += 256) {
        int q = idx >> 7, d = idx & 127;
        float w = wtile[q * 132 + d] - capC[(size_t)q * DD + d0 + d];
        wtile[q * 132 + d] = w * w;
      }
      __syncthreads();
      for (int sub = 0; sub < 4; ++sub) {
        float4 wv[8];
#pragma unroll
        for (int u = 0; u < 8; ++u)
          wv[u] = *(const float4*)&W_loc[(size_t)(d0 + sub * 32 + l_dd) * SS + l_cq * 32 + u * 4];
        __syncthreads();
#pragma unroll
        for (int u = 0; u < 8; ++u)
          *(float4*)&wloc[l_dd * 260 + l_cq * 32 + u * 4] = wv[u];
        __syncthreads();
        for (int dd = 0; dd < 32; ++dd) {
          float d2v[4];
#pragma unroll
          for (int i = 0; i < 4; ++i)
            d2v[i] = wtile[(sq * 4 + i) * 132 + sub * 32 + dd];
          float4 wl0 = *(const float4*)&wloc[dd * 260 + sg * 8];
          float4 wl1 = *(const float4*)&wloc[dd * 260 + sg * 8 + 4];
          float wlv[8] = {wl0.x, wl0.y, wl0.z, wl0.w, wl1.x, wl1.y, wl1.z, wl1.w};
#pragma unroll
          for (int i = 0; i < 4; ++i)
#pragma unroll
            for (int j = 0; j < 8; ++j) sl[i][j] += d2v[i] * wlv[j];
        }
        __syncthreads();
      }
    }
  }
  __syncthreads();

  // ---------------- sim_emb assembly: l2norm(sim_loc)+bias, sim_glo row 0
  {
    int sq = tid >> 5, sg = tid & 31;
#pragma unroll
    for (int i = 0; i < 4; ++i) {
      float v[8];
      float ssq = 0.f;
#pragma unroll
      for (int j = 0; j < 8; ++j) {
        v[j] = sl[i][j] + b_loc[sg * 8 + j];
        ssq += v[j] * v[j];
      }
      ssq += __shfl_xor(ssq, 1, 64);
      ssq += __shfl_xor(ssq, 2, 64);
      ssq += __shfl_xor(ssq, 4, 64);
      ssq += __shfl_xor(ssq, 8, 64);
      ssq += __shfl_xor(ssq, 16, 64);
      float rn = 1.0f / fmaxf(sqrtf(ssq), EPSN);
      int q = sq * 4 + i;
      *(float4*)&seA[(1 + q) * 260 + sg * 8] =
          make_float4(v[0] * rn, v[1] * rn, v[2] * rn, v[3] * rn);
      *(float4*)&seA[(1 + q) * 260 + sg * 8 + 4] =
          make_float4(v[4] * rn, v[5] * rn, v[6] * rn, v[7] * rn);
    }
    if (tid < 64)
      *(float4*)&seA[tid * 4] = *(const float4*)&simglo[(size_t)p * SS + tid * 4];
  }
  __syncthreads();

  // ---------------- SGR x3
  int tx = tid & 31, ty = tid >> 5;
  for (int step = 0; step < 3; ++step) {
    const float* Ms = M + (size_t)step * SS * SS;
    const float* Wgs = Wg3 + (size_t)step * SS * SS;
    const float* bgs = bg3 + (size_t)step * SS;
    if (tid < 64)
      *(float4*)&wkbqs[tid * 4] = *(const float4*)&wkbq[step * SS + tid * 4];
    __syncthreads();
    // (a) t1 = seA @ M -> seB
    {
      float acc[4][8] = {};
      float accx[8] = {};
      for (int k = 0; k < SS; ++k) {
        float av[4];
        av[0] = seA[(ty + 0) * 260 + k];
        av[1] = seA[(ty + 8) * 260 + k];
        av[2] = seA[(ty + 16) * 260 + k];
        av[3] = seA[(ty + 24) * 260 + k];
        float4 m0 = *(const float4*)&Ms[(size_t)k * SS + tx * 8];
        float4 m1 = *(const float4*)&Ms[(size_t)k * SS + tx * 8 + 4];
        float mv[8] = {m0.x, m0.y, m0.z, m0.w, m1.x, m1.y, m1.z, m1.w};
#pragma unroll
        for (int i = 0; i < 4; ++i)
#pragma unroll
          for (int j = 0; j < 8; ++j) acc[i][j] += av[i] * mv[j];
        if (ty == 0) {
          float ax = seA[32 * 260 + k];
#pragma unroll
          for (int j = 0; j < 8; ++j) accx[j] += ax * mv[j];
        }
      }
#pragma unroll
      for (int i = 0; i < 4; ++i) {
        *(float4*)&seB[(ty + 8 * i) * 260 + tx * 8] =
            make_float4(acc[i][0], acc[i][1], acc[i][2], acc[i][3]);
        *(float4*)&seB[(ty + 8 * i) * 260 + tx * 8 + 4] =
            make_float4(acc[i][4], acc[i][5], acc[i][6], acc[i][7]);
      }
      if (ty == 0) {
        *(float4*)&seB[32 * 260 + tx * 8] = make_float4(accx[0], accx[1], accx[2], accx[3]);
        *(float4*)&seB[32 * 260 + tx * 8 + 4] = make_float4(accx[4], accx[5], accx[6], accx[7]);
      }
    }
    __syncthreads();
    // (b) v[m] = seA[m] . wkbq
    if (tid < NN) {
      float a = 0.f;
      for (int e = 0; e < SS; e += 4) {
        float4 s4 = *(const float4*)&seA[tid * 260 + e];
        float4 w4 = *(const float4*)&wkbqs[e];
        a += s4.x * w4.x + s4.y * w4.y + s4.z * w4.z + s4.w * w4.w;
      }
      vbuf[tid] = a;
    }
    __syncthreads();
    // (c) E[n][m] = t1[n].seA[m] + v[m]
    for (int idx = tid; idx < NN * NN; idx += 256) {
      int n = idx / NN, mm = idx - n * NN;
      float a = 0.f;
      for (int e = 0; e < SS; e += 4) {
        float4 t4 = *(const float4*)&seB[n * 260 + e];
        float4 s4 = *(const float4*)&seA[mm * 260 + e];
        a += t4.x * s4.x + t4.y * s4.y + t4.z * s4.z + t4.w * s4.w;
      }
      Emat[n * 36 + mm] = a + vbuf[mm];
    }
    __syncthreads();
    // (d) row softmax of E
    if (tid < NN) {
      float mx = -1e30f;
      for (int mm = 0; mm < NN; ++mm) mx = fmaxf(mx, Emat[tid * 36 + mm]);
      float sum = 0.f;
      for (int mm = 0; mm < NN; ++mm) {
        float e = expf(Emat[tid * 36 + mm] - mx);
        Emat[tid * 36 + mm] = e;
        sum += e;
      }
      float rs = 1.0f / sum;
      for (int mm = 0; mm < NN; ++mm) Emat[tid * 36 + mm] *= rs;
    }
    __syncthreads();
    // (e) sgr = E @ seA -> seB
    {
      float acc[4][8] = {};
      float accx[8] = {};
      for (int mm = 0; mm < NN; ++mm) {
        float ev[4];
        ev[0] = Emat[(ty + 0) * 36 + mm];
        ev[1] = Emat[(ty + 8) * 36 + mm];
        ev[2] = Emat[(ty + 16) * 36 + mm];
        ev[3] = Emat[(ty + 24) * 36 + mm];
        float4 s0 = *(const float4*)&seA[mm * 260 + tx * 8];
        float4 s1 = *(const float4*)&seA[mm * 260 + tx * 8 + 4];
        float sv[8] = {s0.x, s0.y, s0.z, s0.w, s1.x, s1.y, s1.z, s1.w};
#pragma unroll
        for (int i = 0; i < 4; ++i)
#pragma unroll
          for (int j = 0; j < 8; ++j) acc[i][j] += ev[i] * sv[j];
        if (ty == 0) {
          float ex = Emat[32 * 36 + mm];
#pragma unroll
          for (int j = 0; j < 8; ++j) accx[j] += ex * sv[j];
        }
      }
      __syncthreads();
#pragma unroll
      for (int i = 0; i < 4; ++i) {
        *(float4*)&seB[(ty + 8 * i) * 260 + tx * 8] =
            make_float4(acc[i][0], acc[i][1], acc[i][2], acc[i][3]);
        *(float4*)&seB[(ty + 8 * i) * 260 + tx * 8 + 4] =
            make_float4(acc[i][4], acc[i][5], acc[i][6], acc[i][7]);
      }
      if (ty == 0) {
        *(float4*)&seB[32 * 260 + tx * 8] = make_float4(accx[0], accx[1], accx[2], accx[3]);
        *(float4*)&seB[32 * 260 + tx * 8 + 4] = make_float4(accx[4], accx[5], accx[6], accx[7]);
      }
    }
    __syncthreads();
    // (f) seA = relu(seB @ Wg + bg)
    {
      float acc[4][8] = {};
      float accx[8] = {};
      for (int k = 0; k < SS; ++k) {
        float av[4];
        av[0] = seB[(ty + 0) * 260 + k];
        av[1] = seB[(ty + 8) * 260 + k];
        av[2] = seB[(ty + 16) * 260 + k];
        av[3] = seB[(ty + 24) * 260 + k];
        float4 w0 = *(const float4*)&Wgs[(size_t)k * SS + tx * 8];
        float4 w1 = *(const float4*)&Wgs[(size_t)k * SS + tx * 8 + 4];
        float wv[8] = {w0.x, w0.y, w0.z, w0.w, w1.x, w1.y, w1.z, w1.w};
#pragma unroll
        for (int i = 0; i < 4; ++i)
#pragma unroll
          for (int j = 0; j < 8; ++j) acc[i][j] += av[i] * wv[j];
        if (ty == 0) {
          float ax = seB[32 * 260 + k];
#pragma unroll
          for (int j = 0; j < 8; ++j) accx[j] += ax * wv[j];
        }
      }
      __syncthreads();
#pragma unroll
      for (int i = 0; i < 4; ++i) {
#pragma unroll
        for (int j = 0; j < 8; ++j) {
          float v = acc[i][j] + bgs[tx * 8 + j];
          acc[i][j] = v > 0.f ? v : 0.f;
        }
        *(float4*)&seA[(ty + 8 * i) * 260 + tx * 8] =
            make_float4(acc[i][0], acc[i][1], acc[i][2], acc[i][3]);
        *(float4*)&seA[(ty + 8 * i) * 260 + tx * 8 + 4] =
            make_float4(acc[i][4], acc[i][5], acc[i][6], acc[i][7]);
      }
      if (ty == 0) {
#pragma unroll
        for (int j = 0; j < 8; ++j) {
          float v = accx[j] + bgs[tx * 8 + j];
          accx[j] = v > 0.f ? v : 0.f;
        }
        *(float4*)&seA[32 * 260 + tx * 8] = make_float4(accx[0], accx[1], accx[2], accx[3]);
        *(float4*)&seA[32 * 260 + tx * 8 + 4] = make_float4(accx[4], accx[5], accx[6], accx[7]);
      }
    }
    __syncthreads();
  }

  // ---------------- eval: sigmoid(seA[0] @ W_eval + b_eval)
  if (tid < 64) {
    float4 s4 = *(const float4*)&seA[tid * 4];
    float4 w4 = *(const float4*)&W_eval[tid * 4];
    float s = s4.x * w4.x + s4.y * w4.y + s4.z * w4.z + s4.w * w4.w;
    s = warp_reduce_sum64(s);
    if (tid == 0) out[b * 64 + c] = 1.0f / (1.0f + expf(-(s + b_eval[0])));
  }
}

extern "C" void kernel_launch(void* const* d_in, const int* in_sizes, int n_in,
                              void* d_out, int out_size, void* d_ws, size_t ws_size,
                              hipStream_t stream) {
  (void)in_sizes; (void)n_in; (void)out_size; (void)ws_size;
  const float* img = (const float*)d_in[0];
  const float* cap = (const float*)d_in[1];
  const float* vG_Wl = (const float*)d_in[3];
  const float* vG_bl = (const float*)d_in[4];
  const float* vG_Wg = (const float*)d_in[5];
  const float* vG_bg = (const float*)d_in[6];
  const float* vG_Wc = (const float*)d_in[7];
  const float* vG_bc = (const float*)d_in[8];
  const float* tG_Wl = (const float*)d_in[9];
  const float* tG_bl = (const float*)d_in[10];
  const float* tG_Wg = (const float*)d_in[11];
  const float* tG_bg = (const float*)d_in[12];
  const float* tG_Wc = (const float*)d_in[13];
  const float* tG_bc = (const float*)d_in[14];
  const float* W_loc = (const float*)d_in[15];
  const float* b_loc = (const float*)d_in[16];
  const float* W_glo = (const float*)d_in[17];
  const float* b_glo = (const float*)d_in[18];
  const float* W_eval = (const float*)d_in[19];
  const float* b_eval = (const float*)d_in[20];
  const float* sgr_Wq = (const float*)d_in[21];
  const float* sgr_bq = (const float*)d_in[22];
  const float* sgr_Wk = (const float*)d_in[23];
  const float* sgr_Wg = (const float*)d_in[25];
  const float* sgr_bg = (const float*)d_in[26];
  float* out = (float*)d_out;
  float* ws = (float*)d_ws;
  float* img_avg = ws;
  float* cap_avg = ws + 65536;
  float* h_img = ws + 131072;
  float* h_cap = ws + 196608;
  float* part_img = ws + 262144;
  float* part_cap = ws + 462848;
  float* img_glob = ws + 495616;
  float* cap_glob = ws + 561152;
  float* simglo = ws + 626688;
  float* Mmat = ws + 1675264;
  float* wkbqv = ws + 1871872;

  k_avg<<<128, 256, 0, stream>>>(img, cap, img_avg, cap_avg);
  k_hvec<<<256, 256, 0, stream>>>(img_avg, vG_Wg, vG_bg, vG_Wc, h_img);
  k_hvec<<<256, 256, 0, stream>>>(cap_avg, tG_Wg, tG_bg, tG_Wc, h_cap);
  k_logits_partial<<<dim3(196, 16), 256, 0, stream>>>(img + DD, (long)NTOK * DD, TT, vG_Wl,
                                                      vG_bl, h_img, part_img);
  k_logits_partial<<<dim3(32, 16), 256, 0, stream>>>(cap, (long)CL * DD, CL, tG_Wl, tG_bl,
                                                     h_cap, part_cap);
  k_finish_global<<<64, 256, 0, stream>>>(part_img, vG_bc, img + DD, (long)NTOK * DD, TT,
                                          img_glob);
  k_finish_global<<<64, 256, 0, stream>>>(part_cap, tG_bc, cap, (long)CL * DD, CL, cap_glob);
  k_simglo<<<256, 256, 0, stream>>>(img_glob, cap_glob, W_glo, b_glo, simglo);
  k_mmat<<<48, 256, 0, stream>>>(sgr_Wq, sgr_Wk, Mmat);
  k_wkbq<<<3, 256, 0, stream>>>(sgr_Wk, sgr_bq, wkbqv);
  hipFuncSetAttribute((const void*)k_pair, hipFuncAttributeMaxDynamicSharedMemorySize,
                      SMEM_BYTES);
  k_pair<<<4096, 256, SMEM_BYTES, stream>>>(img, cap, W_loc, b_loc, simglo, Mmat, wkbqv,
                                            sgr_Wg, sgr_bg, W_eval, b_eval, out);
}